// Round 1
// baseline (770.944 us; speedup 1.0000x reference)
//
#include <hip/hip_runtime.h>
#include <hip/hip_bf16.h>
#include <math.h>

// Problem constants
#define BATCH 4
#define LSEQ 2048
#define DMODEL 512
#define NHEADS 8
#define EDIM 64
#define SAMPK 40
#define NTOP 40
#define BHTOT (BATCH * NHEADS)
#define MROWS (BATCH * LSEQ)   // 8192

// ---------------------------------------------------------------------------
// GEMM: P = X @ W + bias.  X: (Mrows, 512) f32, W: (512,512) f32 row-major.
// 64x64 tile per block, 256 threads, 4x4 micro-tile, K-tile 16.
// ---------------------------------------------------------------------------
__global__ __launch_bounds__(256) void gemm_bias(const float* __restrict__ X,
                                                 const float* __restrict__ W,
                                                 const float* __restrict__ bias,
                                                 float* __restrict__ P) {
    __shared__ float Xs[16][64 + 4];
    __shared__ float Ws[16][64 + 4];
    const int tid = threadIdx.x;
    const int tx = tid & 15, ty = tid >> 4;
    const int m0 = blockIdx.x * 64;
    const int n0 = blockIdx.y * 64;

    float acc[4][4] = {};

    for (int kt = 0; kt < DMODEL; kt += 16) {
        // stage X tile (64 rows x 16 k): each thread loads float4 along k
        {
            int r  = tid >> 2;          // 0..63
            int kk = (tid & 3) * 4;     // 0,4,8,12
            float4 xv = *reinterpret_cast<const float4*>(&X[(size_t)(m0 + r) * DMODEL + kt + kk]);
            Xs[kk + 0][r] = xv.x; Xs[kk + 1][r] = xv.y;
            Xs[kk + 2][r] = xv.z; Xs[kk + 3][r] = xv.w;
        }
        // stage W tile (16 k x 64 n)
        {
            int kk = tid >> 4;          // 0..15
            int nn = (tid & 15) * 4;    // 0..60
            float4 wv = *reinterpret_cast<const float4*>(&W[(size_t)(kt + kk) * DMODEL + n0 + nn]);
            *reinterpret_cast<float4*>(&Ws[kk][nn]) = wv;
        }
        __syncthreads();
        #pragma unroll
        for (int kk = 0; kk < 16; ++kk) {
            float a[4], b[4];
            #pragma unroll
            for (int i = 0; i < 4; ++i) a[i] = Xs[kk][ty * 4 + i];
            #pragma unroll
            for (int j = 0; j < 4; ++j) b[j] = Ws[kk][tx * 4 + j];
            #pragma unroll
            for (int i = 0; i < 4; ++i)
                #pragma unroll
                for (int j = 0; j < 4; ++j)
                    acc[i][j] = fmaf(a[i], b[j], acc[i][j]);
        }
        __syncthreads();
    }
    #pragma unroll
    for (int i = 0; i < 4; ++i) {
        int m = m0 + ty * 4 + i;
        #pragma unroll
        for (int j = 0; j < 4; ++j) {
            int n = n0 + tx * 4 + j;
            P[(size_t)m * DMODEL + n] = acc[i][j] + bias[n];
        }
    }
}

// ---------------------------------------------------------------------------
// M[b,h,l] = max_s dot(q_l, k_samp) - sum_s dot(q_l, k_samp) / L
// One wave (64 lanes) per (bh,l); lane = e.
// ---------------------------------------------------------------------------
__global__ __launch_bounds__(256) void m_kernel(const float* __restrict__ Qp,
                                                const float* __restrict__ Kp,
                                                const int* __restrict__ samp,
                                                float* __restrict__ M) {
    const int wid = threadIdx.x >> 6;
    const int lane = threadIdx.x & 63;
    const int gl = blockIdx.x * 4 + wid;           // (bh, l) flat
    const int bh = gl >> 11;
    const int l  = gl & (LSEQ - 1);
    const float qv = Qp[(size_t)gl * EDIM + lane];
    const float* Kb = Kp + (size_t)bh * LSEQ * EDIM;

    float mx = -INFINITY, sm = 0.f;
    for (int s = 0; s < SAMPK; ++s) {
        int idx = samp[l * SAMPK + s];
        float p = qv * Kb[(size_t)idx * EDIM + lane];
        // 64-lane butterfly sum
        #pragma unroll
        for (int off = 32; off >= 1; off >>= 1) p += __shfl_xor(p, off);
        mx = fmaxf(mx, p);
        sm += p;
    }
    if (lane == 0) M[gl] = mx - sm * (1.0f / (float)LSEQ);
}

// ---------------------------------------------------------------------------
// Top-40 indices of M[bh, 0..2047]  (iterative argmax, ties -> lower index)
// ---------------------------------------------------------------------------
__global__ __launch_bounds__(256) void topk_kernel(const float* __restrict__ M,
                                                   int* __restrict__ topk) {
    __shared__ float vals[LSEQ];
    __shared__ float rv[256];
    __shared__ int   ri[256];
    const int bh = blockIdx.x, tid = threadIdx.x;
    for (int i = tid; i < LSEQ; i += 256) vals[i] = M[bh * LSEQ + i];
    __syncthreads();
    for (int t = 0; t < NTOP; ++t) {
        float best = -INFINITY; int bi = LSEQ;
        for (int i = tid; i < LSEQ; i += 256) {
            float v = vals[i];
            if (v > best || (v == best && i < bi)) { best = v; bi = i; }
        }
        rv[tid] = best; ri[tid] = bi;
        __syncthreads();
        for (int s = 128; s >= 1; s >>= 1) {
            if (tid < s) {
                float v2 = rv[tid + s]; int i2 = ri[tid + s];
                if (v2 > rv[tid] || (v2 == rv[tid] && i2 < ri[tid])) { rv[tid] = v2; ri[tid] = i2; }
            }
            __syncthreads();
        }
        if (tid == 0) { topk[bh * NTOP + t] = ri[0]; vals[ri[0]] = -INFINITY; }
        __syncthreads();
    }
}

// ---------------------------------------------------------------------------
// Cumsum of V over l, 3-phase. NCHUNK=32 chunks of 64 rows.
// ---------------------------------------------------------------------------
#define NCHUNK 32
#define CHLEN  64
__global__ __launch_bounds__(64) void cs1(const float* __restrict__ Vp, float* __restrict__ part) {
    const int bh = blockIdx.x >> 5, c = blockIdx.x & 31, e = threadIdx.x;
    const float* vb = Vp + ((size_t)bh * LSEQ + (size_t)c * CHLEN) * EDIM;
    float s = 0.f;
    for (int l = 0; l < CHLEN; ++l) s += vb[(size_t)l * EDIM + e];
    part[((size_t)bh * NCHUNK + c) * EDIM + e] = s;
}
__global__ __launch_bounds__(256) void cs2(float* __restrict__ part) {
    const int t = blockIdx.x * 256 + threadIdx.x;   // 0..2047 = (bh,e)
    const int bh = t >> 6, e = t & 63;
    float run = 0.f;
    for (int c = 0; c < NCHUNK; ++c) {
        float* p = &part[((size_t)bh * NCHUNK + c) * EDIM + e];
        float v = *p; *p = run; run += v;
    }
}
__global__ __launch_bounds__(64) void cs3(const float* __restrict__ Vp,
                                          const float* __restrict__ part,
                                          float* __restrict__ out) {
    const int bh = blockIdx.x >> 5, c = blockIdx.x & 31, e = threadIdx.x;
    const float* vb = Vp + ((size_t)bh * LSEQ + (size_t)c * CHLEN) * EDIM;
    float* ob = out + ((size_t)bh * LSEQ + (size_t)c * CHLEN) * EDIM;
    float run = part[((size_t)bh * NCHUNK + c) * EDIM + e];
    for (int l = 0; l < CHLEN; ++l) {
        run += vb[(size_t)l * EDIM + e];
        ob[(size_t)l * EDIM + e] = run;
    }
}

// ---------------------------------------------------------------------------
// Full causal attention for selected queries; overwrites their output rows.
// One block (256 thr) per (bh, n).
// ---------------------------------------------------------------------------
__global__ __launch_bounds__(256) void attn_kernel(const float* __restrict__ Qp,
                                                   const float* __restrict__ Kp,
                                                   const float* __restrict__ Vp,
                                                   const int* __restrict__ topk,
                                                   float* __restrict__ out) {
    __shared__ float q[EDIM];
    __shared__ float sc[LSEQ];
    __shared__ float red[256];
    __shared__ float pacc[4][EDIM];
    const int bh = blockIdx.x / NTOP, n = blockIdx.x % NTOP;
    const int idx = topk[bh * NTOP + n];
    const int tid = threadIdx.x;

    if (tid < EDIM) q[tid] = Qp[((size_t)bh * LSEQ + idx) * EDIM + tid];
    __syncthreads();

    float lmax = -INFINITY;
    for (int j = tid; j <= idx; j += 256) {
        const float4* kr = reinterpret_cast<const float4*>(Kp + ((size_t)bh * LSEQ + j) * EDIM);
        float s = 0.f;
        #pragma unroll
        for (int e4 = 0; e4 < 16; ++e4) {
            float4 kv = kr[e4];
            s += q[e4 * 4 + 0] * kv.x + q[e4 * 4 + 1] * kv.y +
                 q[e4 * 4 + 2] * kv.z + q[e4 * 4 + 3] * kv.w;
        }
        s *= 0.125f;   // 1/sqrt(64)
        sc[j] = s;
        lmax = fmaxf(lmax, s);
    }
    red[tid] = lmax; __syncthreads();
    for (int s = 128; s >= 1; s >>= 1) { if (tid < s) red[tid] = fmaxf(red[tid], red[tid + s]); __syncthreads(); }
    const float mx = red[0];
    __syncthreads();

    float lsum = 0.f;
    for (int j = tid; j <= idx; j += 256) {
        float p = __expf(sc[j] - mx);
        sc[j] = p;
        lsum += p;
    }
    red[tid] = lsum; __syncthreads();
    for (int s = 128; s >= 1; s >>= 1) { if (tid < s) red[tid] += red[tid + s]; __syncthreads(); }
    const float inv = 1.0f / red[0];
    __syncthreads();

    const int e = tid & 63, part = tid >> 6;
    float a = 0.f;
    for (int j = part; j <= idx; j += 4)
        a += sc[j] * Vp[((size_t)bh * LSEQ + j) * EDIM + e];
    pacc[part][e] = a;
    __syncthreads();
    if (tid < EDIM) {
        float o = (pacc[0][tid] + pacc[1][tid] + pacc[2][tid] + pacc[3][tid]) * inv;
        out[((size_t)bh * LSEQ + idx) * EDIM + tid] = o;
    }
}

// ---------------------------------------------------------------------------
extern "C" void kernel_launch(void* const* d_in, const int* in_sizes, int n_in,
                              void* d_out, int out_size, void* d_ws, size_t ws_size,
                              hipStream_t stream) {
    const float* q  = (const float*)d_in[0];
    const float* k  = (const float*)d_in[1];
    const float* v  = (const float*)d_in[2];
    // d_in[3] = mask (unused)
    const float* Wq = (const float*)d_in[4];
    const float* bq = (const float*)d_in[5];
    const float* Wk = (const float*)d_in[6];
    const float* bk = (const float*)d_in[7];
    const float* Wv = (const float*)d_in[8];
    const float* bv = (const float*)d_in[9];
    const int* samp = (const int*)d_in[10];
    float* out = (float*)d_out;

    float* ws = (float*)d_ws;
    const size_t NPROJ = (size_t)MROWS * DMODEL;   // 4194304
    float* Qp   = ws;
    float* Kp   = Qp + NPROJ;
    float* Vp   = Kp + NPROJ;
    float* Mbuf = Vp + NPROJ;                       // 65536
    float* part = Mbuf + (size_t)BHTOT * LSEQ;      // 65536
    int*  topk  = (int*)(part + (size_t)BHTOT * NCHUNK * EDIM);

    dim3 ggrid(MROWS / 64, DMODEL / 64);
    gemm_bias<<<ggrid, 256, 0, stream>>>(q, Wq, bq, Qp);
    gemm_bias<<<ggrid, 256, 0, stream>>>(k, Wk, bk, Kp);
    gemm_bias<<<ggrid, 256, 0, stream>>>(v, Wv, bv, Vp);

    m_kernel<<<BHTOT * LSEQ / 4, 256, 0, stream>>>(Qp, Kp, samp, Mbuf);
    topk_kernel<<<BHTOT, 256, 0, stream>>>(Mbuf, topk);

    cs1<<<BHTOT * NCHUNK, 64, 0, stream>>>(Vp, part);
    cs2<<<8, 256, 0, stream>>>(part);
    cs3<<<BHTOT * NCHUNK, 64, 0, stream>>>(Vp, part, out);

    attn_kernel<<<BHTOT * NTOP, 256, 0, stream>>>(Qp, Kp, Vp, topk, out);
}

// Round 6
// 716.826 us; speedup vs baseline: 1.0755x; 1.0755x over previous
//
#include <hip/hip_runtime.h>
#include <hip/hip_bf16.h>
#include <math.h>

// Problem constants
#define BATCH 4
#define LSEQ 2048
#define DMODEL 512
#define NHEADS 8
#define EDIM 64
#define SAMPK 40
#define NTOP 40
#define BHTOT (BATCH * NHEADS)
#define MROWS (BATCH * LSEQ)   // 8192
#define JC 256                  // attn split-K chunk
#define NCHMAX 8                // LSEQ / JC

// ---------------------------------------------------------------------------
// GEMM: P = X @ W + bias.  X: (8192, 512) f32, W: (512,512) f32 row-major.
// 128x128 tile per block, 256 threads, 8x(4+4) micro-tile, K-tile 16.
// NOTE: must stay f32 — bf16 projections perturb M-scores enough to flip
// top-40 selection (gap between 40th/41st order stats ~0.01-0.05 < bf16
// dot error ~0.1), and a flipped index costs absmax ~45 >> 3.38.
// ---------------------------------------------------------------------------
__global__ __launch_bounds__(256) void gemm_bias(const float* __restrict__ X,
                                                 const float* __restrict__ W,
                                                 const float* __restrict__ bias,
                                                 float* __restrict__ P) {
    __shared__ float Xs[16][128 + 4];
    __shared__ float Ws[16][128 + 4];
    const int tid = threadIdx.x;
    const int tx = tid & 15;          // n group: cols tx*4..+3 and 64+tx*4..+3
    const int ty = tid >> 4;          // m group: rows ty*8..+7
    const int m0 = blockIdx.x * 128;
    const int n0 = blockIdx.y * 128;

    float acc0[8][4] = {};
    float acc1[8][4] = {};

    for (int kt = 0; kt < DMODEL; kt += 16) {
        // stage X tile (128 rows x 16 k): thread -> row tid>>1, k-half (tid&1)*8
        {
            int r  = tid >> 1;
            int kk = (tid & 1) * 8;
            const float* src = &X[(size_t)(m0 + r) * DMODEL + kt + kk];
            float4 x0 = *reinterpret_cast<const float4*>(src);
            float4 x1 = *reinterpret_cast<const float4*>(src + 4);
            Xs[kk + 0][r] = x0.x; Xs[kk + 1][r] = x0.y;
            Xs[kk + 2][r] = x0.z; Xs[kk + 3][r] = x0.w;
            Xs[kk + 4][r] = x1.x; Xs[kk + 5][r] = x1.y;
            Xs[kk + 6][r] = x1.z; Xs[kk + 7][r] = x1.w;
        }
        // stage W tile (16 k x 128 n): thread -> k row tid>>4, n chunk (tid&15)*8
        {
            int kk = tid >> 4;
            int nn = (tid & 15) * 8;
            const float* src = &W[(size_t)(kt + kk) * DMODEL + n0 + nn];
            float4 w0 = *reinterpret_cast<const float4*>(src);
            float4 w1 = *reinterpret_cast<const float4*>(src + 4);
            *reinterpret_cast<float4*>(&Ws[kk][nn]) = w0;
            *reinterpret_cast<float4*>(&Ws[kk][nn + 4]) = w1;
        }
        __syncthreads();
        #pragma unroll
        for (int kk = 0; kk < 16; ++kk) {
            float a[8], b0[4], b1[4];
            #pragma unroll
            for (int i = 0; i < 8; ++i) a[i] = Xs[kk][ty * 8 + i];
            #pragma unroll
            for (int j = 0; j < 4; ++j) b0[j] = Ws[kk][tx * 4 + j];
            #pragma unroll
            for (int j = 0; j < 4; ++j) b1[j] = Ws[kk][64 + tx * 4 + j];
            #pragma unroll
            for (int i = 0; i < 8; ++i) {
                #pragma unroll
                for (int j = 0; j < 4; ++j) {
                    acc0[i][j] = fmaf(a[i], b0[j], acc0[i][j]);
                    acc1[i][j] = fmaf(a[i], b1[j], acc1[i][j]);
                }
            }
        }
        __syncthreads();
    }
    #pragma unroll
    for (int i = 0; i < 8; ++i) {
        int m = m0 + ty * 8 + i;
        float4 o0, o1;
        o0.x = acc0[i][0] + bias[n0 + tx * 4 + 0];
        o0.y = acc0[i][1] + bias[n0 + tx * 4 + 1];
        o0.z = acc0[i][2] + bias[n0 + tx * 4 + 2];
        o0.w = acc0[i][3] + bias[n0 + tx * 4 + 3];
        o1.x = acc1[i][0] + bias[n0 + 64 + tx * 4 + 0];
        o1.y = acc1[i][1] + bias[n0 + 64 + tx * 4 + 1];
        o1.z = acc1[i][2] + bias[n0 + 64 + tx * 4 + 2];
        o1.w = acc1[i][3] + bias[n0 + 64 + tx * 4 + 3];
        *reinterpret_cast<float4*>(&P[(size_t)m * DMODEL + n0 + tx * 4]) = o0;
        *reinterpret_cast<float4*>(&P[(size_t)m * DMODEL + n0 + 64 + tx * 4]) = o1;
    }
}

// ---------------------------------------------------------------------------
// M[b,h,l] = max_s dot(q_l, k_samp) - sum_s dot(q_l, k_samp) / L
// One wave (64 lanes) per (bh,l); lane = e.
// ---------------------------------------------------------------------------
__global__ __launch_bounds__(256) void m_kernel(const float* __restrict__ Qp,
                                                const float* __restrict__ Kp,
                                                const int* __restrict__ samp,
                                                float* __restrict__ M) {
    const int wid = threadIdx.x >> 6;
    const int lane = threadIdx.x & 63;
    const int gl = blockIdx.x * 4 + wid;           // (bh, l) flat
    const int bh = gl >> 11;
    const int l  = gl & (LSEQ - 1);
    const float qv = Qp[(size_t)gl * EDIM + lane];
    const float* Kb = Kp + (size_t)bh * LSEQ * EDIM;

    float mx = -INFINITY, sm = 0.f;
    for (int s = 0; s < SAMPK; ++s) {
        int idx = samp[l * SAMPK + s];
        float p = qv * Kb[(size_t)idx * EDIM + lane];
        #pragma unroll
        for (int off = 32; off >= 1; off >>= 1) p += __shfl_xor(p, off);
        mx = fmaxf(mx, p);
        sm += p;
    }
    if (lane == 0) M[gl] = mx - sm * (1.0f / (float)LSEQ);
}

// ---------------------------------------------------------------------------
// Top-40 indices of M[bh, 0..2047]  (iterative argmax, ties -> lower index)
// ---------------------------------------------------------------------------
__global__ __launch_bounds__(256) void topk_kernel(const float* __restrict__ M,
                                                   int* __restrict__ topk) {
    __shared__ float vals[LSEQ];
    __shared__ float rv[256];
    __shared__ int   ri[256];
    const int bh = blockIdx.x, tid = threadIdx.x;
    for (int i = tid; i < LSEQ; i += 256) vals[i] = M[bh * LSEQ + i];
    __syncthreads();
    for (int t = 0; t < NTOP; ++t) {
        float best = -INFINITY; int bi = LSEQ;
        for (int i = tid; i < LSEQ; i += 256) {
            float v = vals[i];
            if (v > best || (v == best && i < bi)) { best = v; bi = i; }
        }
        rv[tid] = best; ri[tid] = bi;
        __syncthreads();
        for (int s = 128; s >= 1; s >>= 1) {
            if (tid < s) {
                float v2 = rv[tid + s]; int i2 = ri[tid + s];
                if (v2 > rv[tid] || (v2 == rv[tid] && i2 < ri[tid])) { rv[tid] = v2; ri[tid] = i2; }
            }
            __syncthreads();
        }
        if (tid == 0) { topk[bh * NTOP + t] = ri[0]; vals[ri[0]] = -INFINITY; }
        __syncthreads();
    }
}

// ---------------------------------------------------------------------------
// Cumsum of V over l, 3-phase. NCHUNK=32 chunks of 64 rows.
// ---------------------------------------------------------------------------
#define NCHUNK 32
#define CHLEN  64
__global__ __launch_bounds__(64) void cs1(const float* __restrict__ Vp, float* __restrict__ part) {
    const int bh = blockIdx.x >> 5, c = blockIdx.x & 31, e = threadIdx.x;
    const float* vb = Vp + ((size_t)bh * LSEQ + (size_t)c * CHLEN) * EDIM;
    float s = 0.f;
    for (int l = 0; l < CHLEN; ++l) s += vb[(size_t)l * EDIM + e];
    part[((size_t)bh * NCHUNK + c) * EDIM + e] = s;
}
__global__ __launch_bounds__(256) void cs2(float* __restrict__ part) {
    const int t = blockIdx.x * 256 + threadIdx.x;   // 0..2047 = (bh,e)
    const int bh = t >> 6, e = t & 63;
    float run = 0.f;
    for (int c = 0; c < NCHUNK; ++c) {
        float* p = &part[((size_t)bh * NCHUNK + c) * EDIM + e];
        float v = *p; *p = run; run += v;
    }
}
__global__ __launch_bounds__(64) void cs3(const float* __restrict__ Vp,
                                          const float* __restrict__ part,
                                          float* __restrict__ out) {
    const int bh = blockIdx.x >> 5, c = blockIdx.x & 31, e = threadIdx.x;
    const float* vb = Vp + ((size_t)bh * LSEQ + (size_t)c * CHLEN) * EDIM;
    float* ob = out + ((size_t)bh * LSEQ + (size_t)c * CHLEN) * EDIM;
    float run = part[((size_t)bh * NCHUNK + c) * EDIM + e];
    for (int l = 0; l < CHLEN; ++l) {
        run += vb[(size_t)l * EDIM + e];
        ob[(size_t)l * EDIM + e] = run;
    }
}

// ---------------------------------------------------------------------------
// Split-K attention partials: one block per (bh*NTOP+n, chunk).
// Writes per-chunk {m, l, acc[64]}.
// ---------------------------------------------------------------------------
__global__ __launch_bounds__(256) void attn_part(const float* __restrict__ Qp,
                                                 const float* __restrict__ Kp,
                                                 const float* __restrict__ Vp,
                                                 const int* __restrict__ topk,
                                                 float* __restrict__ Pm,
                                                 float* __restrict__ Pl,
                                                 float* __restrict__ Pacc) {
    __shared__ float q[EDIM];
    __shared__ float ps[JC];
    __shared__ float red[256];
    __shared__ float pacc[4][EDIM];
    const int gl = blockIdx.y;                  // bh*NTOP + n
    const int bh = gl / NTOP;
    const int idx = topk[gl];
    const int c0 = blockIdx.x * JC;
    if (c0 > idx) return;
    const int tid = threadIdx.x;

    if (tid < EDIM) q[tid] = Qp[((size_t)bh * LSEQ + idx) * EDIM + tid];
    __syncthreads();

    const int j = c0 + tid;
    const bool valid = (j <= idx);
    float s = -INFINITY;
    if (valid) {
        const float4* kr = reinterpret_cast<const float4*>(Kp + ((size_t)bh * LSEQ + j) * EDIM);
        float acc = 0.f;
        #pragma unroll
        for (int e4 = 0; e4 < 16; ++e4) {
            float4 kv = kr[e4];
            acc += q[e4 * 4 + 0] * kv.x + q[e4 * 4 + 1] * kv.y +
                   q[e4 * 4 + 2] * kv.z + q[e4 * 4 + 3] * kv.w;
        }
        s = acc * 0.125f;   // 1/sqrt(64)
    }
    // chunk max
    red[tid] = s; __syncthreads();
    for (int t = 128; t >= 1; t >>= 1) { if (tid < t) red[tid] = fmaxf(red[tid], red[tid + t]); __syncthreads(); }
    const float mc = red[0];
    __syncthreads();
    // exp + chunk sum
    float p = valid ? __expf(s - mc) : 0.f;
    ps[tid] = p;
    red[tid] = p; __syncthreads();
    for (int t = 128; t >= 1; t >>= 1) { if (tid < t) red[tid] += red[tid + t]; __syncthreads(); }
    const float lc = red[0];
    __syncthreads();

    // PV over this chunk: 4 j-partitions x 64 e
    const int e = tid & 63, part = tid >> 6;
    float a = 0.f;
    for (int jj = part; jj < JC; jj += 4)
        a += ps[jj] * Vp[((size_t)bh * LSEQ + c0 + jj) * EDIM + e];
    pacc[part][e] = a;
    __syncthreads();
    if (tid < EDIM) {
        float o = pacc[0][tid] + pacc[1][tid] + pacc[2][tid] + pacc[3][tid];
        Pacc[((size_t)gl * NCHMAX + blockIdx.x) * EDIM + tid] = o;
        if (tid == 0) {
            Pm[gl * NCHMAX + blockIdx.x] = mc;
            Pl[gl * NCHMAX + blockIdx.x] = lc;
        }
    }
}

// ---------------------------------------------------------------------------
// Combine chunk partials -> final attention row, overwrite out.
// One block (64 threads) per (bh, n).
// ---------------------------------------------------------------------------
__global__ __launch_bounds__(64) void attn_reduce(const float* __restrict__ Pm,
                                                  const float* __restrict__ Pl,
                                                  const float* __restrict__ Pacc,
                                                  const int* __restrict__ topk,
                                                  float* __restrict__ out) {
    const int gl = blockIdx.x;
    const int bh = gl / NTOP;
    const int idx = topk[gl];
    const int nch = (idx / JC) + 1;
    const int e = threadIdx.x;

    float M = -INFINITY;
    for (int c = 0; c < nch; ++c) M = fmaxf(M, Pm[gl * NCHMAX + c]);
    float L = 0.f, o = 0.f;
    for (int c = 0; c < nch; ++c) {
        float w = __expf(Pm[gl * NCHMAX + c] - M);
        L += Pl[gl * NCHMAX + c] * w;
        o += Pacc[((size_t)gl * NCHMAX + c) * EDIM + e] * w;
    }
    out[((size_t)bh * LSEQ + idx) * EDIM + e] = o / L;
}

// ---------------------------------------------------------------------------
extern "C" void kernel_launch(void* const* d_in, const int* in_sizes, int n_in,
                              void* d_out, int out_size, void* d_ws, size_t ws_size,
                              hipStream_t stream) {
    const float* q  = (const float*)d_in[0];
    const float* k  = (const float*)d_in[1];
    const float* v  = (const float*)d_in[2];
    const float* Wq = (const float*)d_in[4];
    const float* bq = (const float*)d_in[5];
    const float* Wk = (const float*)d_in[6];
    const float* bk = (const float*)d_in[7];
    const float* Wv = (const float*)d_in[8];
    const float* bv = (const float*)d_in[9];
    const int* samp = (const int*)d_in[10];
    float* out = (float*)d_out;

    float* ws = (float*)d_ws;
    const size_t NPROJ = (size_t)MROWS * DMODEL;    // 4194304
    float* Qp   = ws;
    float* Kp   = Qp + NPROJ;
    float* Vp   = Kp + NPROJ;
    float* Mbuf = Vp + NPROJ;                        // 65536
    float* part = Mbuf + (size_t)BHTOT * LSEQ;       // 65536
    int*  topk  = (int*)(part + (size_t)BHTOT * NCHUNK * EDIM);   // 1280 ints
    float* Pm   = (float*)(topk + BHTOT * NTOP);
    float* Pl   = Pm + (size_t)BHTOT * NTOP * NCHMAX;              // 10240
    float* Pacc = Pl + (size_t)BHTOT * NTOP * NCHMAX;              // 10240
    // Pacc: 1280*8*64 = 655360 floats

    dim3 ggrid(MROWS / 128, DMODEL / 128);
    gemm_bias<<<ggrid, 256, 0, stream>>>(q, Wq, bq, Qp);
    gemm_bias<<<ggrid, 256, 0, stream>>>(k, Wk, bk, Kp);
    gemm_bias<<<ggrid, 256, 0, stream>>>(v, Wv, bv, Vp);

    m_kernel<<<BHTOT * LSEQ / 4, 256, 0, stream>>>(Qp, Kp, samp, Mbuf);
    topk_kernel<<<BHTOT, 256, 0, stream>>>(Mbuf, topk);

    cs1<<<BHTOT * NCHUNK, 64, 0, stream>>>(Vp, part);
    cs2<<<8, 256, 0, stream>>>(part);
    cs3<<<BHTOT * NCHUNK, 64, 0, stream>>>(Vp, part, out);

    attn_part<<<dim3(NCHMAX, BHTOT * NTOP), 256, 0, stream>>>(Qp, Kp, Vp, topk, Pm, Pl, Pacc);
    attn_reduce<<<BHTOT * NTOP, 64, 0, stream>>>(Pm, Pl, Pacc, topk, out);
}

// Round 10
// 586.586 us; speedup vs baseline: 1.3143x; 1.2220x over previous
//
#include <hip/hip_runtime.h>
#include <hip/hip_bf16.h>
#include <math.h>

// Problem constants
#define BATCH 4
#define LSEQ 2048
#define DMODEL 512
#define NHEADS 8
#define EDIM 64
#define SAMPK 40
#define NTOP 40
#define BHTOT (BATCH * NHEADS)
#define MROWS (BATCH * LSEQ)   // 8192
#define JC 256                  // attn split-K chunk
#define NCHMAX 8                // LSEQ / JC

// ---------------------------------------------------------------------------
// GEMM: P = X @ W + bias.  X: (8192, 512) f32, W: (512,512) f32 row-major.
// 128x128 tile per block, 256 threads, 8x(4+4) micro-tile, K-tile 16.
// NOTE: must stay f32-accurate — plain bf16 projections perturb M-scores
// enough to flip top-40 selection (order-stat gap ~0.01-0.05 < bf16 dot
// error ~0.03), and a flipped index costs absmax ~45 >> 3.38. Split-bf16
// (hi+lo, 3x MFMA, ~1e-4 rel err) is the planned safe upgrade.
// ---------------------------------------------------------------------------
__global__ __launch_bounds__(256) void gemm_bias(const float* __restrict__ X,
                                                 const float* __restrict__ W,
                                                 const float* __restrict__ bias,
                                                 float* __restrict__ P) {
    __shared__ float Xs[16][128 + 4];
    __shared__ float Ws[16][128 + 4];
    const int tid = threadIdx.x;
    const int tx = tid & 15;          // n group: cols tx*4..+3 and 64+tx*4..+3
    const int ty = tid >> 4;          // m group: rows ty*8..+7
    const int m0 = blockIdx.x * 128;
    const int n0 = blockIdx.y * 128;

    float acc0[8][4] = {};
    float acc1[8][4] = {};

    for (int kt = 0; kt < DMODEL; kt += 16) {
        // stage X tile (128 rows x 16 k): thread -> row tid>>1, k-half (tid&1)*8
        {
            int r  = tid >> 1;
            int kk = (tid & 1) * 8;
            const float* src = &X[(size_t)(m0 + r) * DMODEL + kt + kk];
            float4 x0 = *reinterpret_cast<const float4*>(src);
            float4 x1 = *reinterpret_cast<const float4*>(src + 4);
            Xs[kk + 0][r] = x0.x; Xs[kk + 1][r] = x0.y;
            Xs[kk + 2][r] = x0.z; Xs[kk + 3][r] = x0.w;
            Xs[kk + 4][r] = x1.x; Xs[kk + 5][r] = x1.y;
            Xs[kk + 6][r] = x1.z; Xs[kk + 7][r] = x1.w;
        }
        // stage W tile (16 k x 128 n): thread -> k row tid>>4, n chunk (tid&15)*8
        {
            int kk = tid >> 4;
            int nn = (tid & 15) * 8;
            const float* src = &W[(size_t)(kt + kk) * DMODEL + n0 + nn];
            float4 w0 = *reinterpret_cast<const float4*>(src);
            float4 w1 = *reinterpret_cast<const float4*>(src + 4);
            *reinterpret_cast<float4*>(&Ws[kk][nn]) = w0;
            *reinterpret_cast<float4*>(&Ws[kk][nn + 4]) = w1;
        }
        __syncthreads();
        #pragma unroll
        for (int kk = 0; kk < 16; ++kk) {
            float a[8], b0[4], b1[4];
            #pragma unroll
            for (int i = 0; i < 8; ++i) a[i] = Xs[kk][ty * 8 + i];
            #pragma unroll
            for (int j = 0; j < 4; ++j) b0[j] = Ws[kk][tx * 4 + j];
            #pragma unroll
            for (int j = 0; j < 4; ++j) b1[j] = Ws[kk][64 + tx * 4 + j];
            #pragma unroll
            for (int i = 0; i < 8; ++i) {
                #pragma unroll
                for (int j = 0; j < 4; ++j) {
                    acc0[i][j] = fmaf(a[i], b0[j], acc0[i][j]);
                    acc1[i][j] = fmaf(a[i], b1[j], acc1[i][j]);
                }
            }
        }
        __syncthreads();
    }
    #pragma unroll
    for (int i = 0; i < 8; ++i) {
        int m = m0 + ty * 8 + i;
        float4 o0, o1;
        o0.x = acc0[i][0] + bias[n0 + tx * 4 + 0];
        o0.y = acc0[i][1] + bias[n0 + tx * 4 + 1];
        o0.z = acc0[i][2] + bias[n0 + tx * 4 + 2];
        o0.w = acc0[i][3] + bias[n0 + tx * 4 + 3];
        o1.x = acc1[i][0] + bias[n0 + 64 + tx * 4 + 0];
        o1.y = acc1[i][1] + bias[n0 + 64 + tx * 4 + 1];
        o1.z = acc1[i][2] + bias[n0 + 64 + tx * 4 + 2];
        o1.w = acc1[i][3] + bias[n0 + 64 + tx * 4 + 3];
        *reinterpret_cast<float4*>(&P[(size_t)m * DMODEL + n0 + tx * 4]) = o0;
        *reinterpret_cast<float4*>(&P[(size_t)m * DMODEL + n0 + 64 + tx * 4]) = o1;
    }
}

// ---------------------------------------------------------------------------
// M[b,h,l] = max_s dot(q_l, k_samp) - sum_s dot(q_l, k_samp) / L
// One wave per (bh,l). Lane = s4*16 + eg: 4 samples/iter, 16 lanes each
// handling float4 of e. 10 iters. Cross-lane ops: 10*4 butterfly + 2 combine
// = 44/wave (was 246 -> DS-op throughput bound at 179 us).
// ---------------------------------------------------------------------------
__global__ __launch_bounds__(256) void m_kernel(const float* __restrict__ Qp,
                                                const float* __restrict__ Kp,
                                                const int* __restrict__ samp,
                                                float* __restrict__ M) {
    const int wid = threadIdx.x >> 6;
    const int lane = threadIdx.x & 63;
    const int gl = blockIdx.x * 4 + wid;           // (bh, l) flat
    const int bh = gl >> 11;
    const int l  = gl & (LSEQ - 1);
    const int s4 = lane >> 4;                      // sample sub-slot 0..3
    const int eg = lane & 15;                      // e-group 0..15

    const float4 qv = *reinterpret_cast<const float4*>(&Qp[(size_t)gl * EDIM + eg * 4]);
    const float* Kb = Kp + (size_t)bh * LSEQ * EDIM;
    const int* srow = samp + l * SAMPK;

    float mx = -INFINITY, sm = 0.f;
    #pragma unroll
    for (int t = 0; t < SAMPK / 4; ++t) {
        const int idx = srow[t * 4 + s4];
        const float4 kv = *reinterpret_cast<const float4*>(&Kb[(size_t)idx * EDIM + eg * 4]);
        float p = qv.x * kv.x + qv.y * kv.y + qv.z * kv.z + qv.w * kv.w;
        // reduce over the 16 lanes of this sample group
        p += __shfl_xor(p, 1);
        p += __shfl_xor(p, 2);
        p += __shfl_xor(p, 4);
        p += __shfl_xor(p, 8);
        mx = fmaxf(mx, p);
        sm += p;
    }
    // combine the 4 sample groups (each lane now has its group's max/sum)
    mx = fmaxf(mx, __shfl_xor(mx, 16));
    sm += __shfl_xor(sm, 16);
    mx = fmaxf(mx, __shfl_xor(mx, 32));
    sm += __shfl_xor(sm, 32);

    if (lane == 0) M[gl] = mx - sm * (1.0f / (float)LSEQ);
}

// ---------------------------------------------------------------------------
// Top-40 indices of M[bh, 0..2047]  (iterative argmax, ties -> lower index)
// ---------------------------------------------------------------------------
__global__ __launch_bounds__(256) void topk_kernel(const float* __restrict__ M,
                                                   int* __restrict__ topk) {
    __shared__ float vals[LSEQ];
    __shared__ float rv[256];
    __shared__ int   ri[256];
    const int bh = blockIdx.x, tid = threadIdx.x;
    for (int i = tid; i < LSEQ; i += 256) vals[i] = M[bh * LSEQ + i];
    __syncthreads();
    for (int t = 0; t < NTOP; ++t) {
        float best = -INFINITY; int bi = LSEQ;
        for (int i = tid; i < LSEQ; i += 256) {
            float v = vals[i];
            if (v > best || (v == best && i < bi)) { best = v; bi = i; }
        }
        rv[tid] = best; ri[tid] = bi;
        __syncthreads();
        for (int s = 128; s >= 1; s >>= 1) {
            if (tid < s) {
                float v2 = rv[tid + s]; int i2 = ri[tid + s];
                if (v2 > rv[tid] || (v2 == rv[tid] && i2 < ri[tid])) { rv[tid] = v2; ri[tid] = i2; }
            }
            __syncthreads();
        }
        if (tid == 0) { topk[bh * NTOP + t] = ri[0]; vals[ri[0]] = -INFINITY; }
        __syncthreads();
    }
}

// ---------------------------------------------------------------------------
// Cumsum of V over l, 3-phase. NCHUNK=32 chunks of 64 rows.
// ---------------------------------------------------------------------------
#define NCHUNK 32
#define CHLEN  64
__global__ __launch_bounds__(64) void cs1(const float* __restrict__ Vp, float* __restrict__ part) {
    const int bh = blockIdx.x >> 5, c = blockIdx.x & 31, e = threadIdx.x;
    const float* vb = Vp + ((size_t)bh * LSEQ + (size_t)c * CHLEN) * EDIM;
    float s = 0.f;
    for (int l = 0; l < CHLEN; ++l) s += vb[(size_t)l * EDIM + e];
    part[((size_t)bh * NCHUNK + c) * EDIM + e] = s;
}
__global__ __launch_bounds__(256) void cs2(float* __restrict__ part) {
    const int t = blockIdx.x * 256 + threadIdx.x;   // 0..2047 = (bh,e)
    const int bh = t >> 6, e = t & 63;
    float run = 0.f;
    for (int c = 0; c < NCHUNK; ++c) {
        float* p = &part[((size_t)bh * NCHUNK + c) * EDIM + e];
        float v = *p; *p = run; run += v;
    }
}
__global__ __launch_bounds__(64) void cs3(const float* __restrict__ Vp,
                                          const float* __restrict__ part,
                                          float* __restrict__ out) {
    const int bh = blockIdx.x >> 5, c = blockIdx.x & 31, e = threadIdx.x;
    const float* vb = Vp + ((size_t)bh * LSEQ + (size_t)c * CHLEN) * EDIM;
    float* ob = out + ((size_t)bh * LSEQ + (size_t)c * CHLEN) * EDIM;
    float run = part[((size_t)bh * NCHUNK + c) * EDIM + e];
    for (int l = 0; l < CHLEN; ++l) {
        run += vb[(size_t)l * EDIM + e];
        ob[(size_t)l * EDIM + e] = run;
    }
}

// ---------------------------------------------------------------------------
// Split-K attention partials: one block per (bh*NTOP+n, chunk).
// Writes per-chunk {m, l, acc[64]}.
// ---------------------------------------------------------------------------
__global__ __launch_bounds__(256) void attn_part(const float* __restrict__ Qp,
                                                 const float* __restrict__ Kp,
                                                 const float* __restrict__ Vp,
                                                 const int* __restrict__ topk,
                                                 float* __restrict__ Pm,
                                                 float* __restrict__ Pl,
                                                 float* __restrict__ Pacc) {
    __shared__ float q[EDIM];
    __shared__ float ps[JC];
    __shared__ float red[256];
    __shared__ float pacc[4][EDIM];
    const int gl = blockIdx.y;                  // bh*NTOP + n
    const int bh = gl / NTOP;
    const int idx = topk[gl];
    const int c0 = blockIdx.x * JC;
    if (c0 > idx) return;
    const int tid = threadIdx.x;

    if (tid < EDIM) q[tid] = Qp[((size_t)bh * LSEQ + idx) * EDIM + tid];
    __syncthreads();

    const int j = c0 + tid;
    const bool valid = (j <= idx);
    float s = -INFINITY;
    if (valid) {
        const float4* kr = reinterpret_cast<const float4*>(Kp + ((size_t)bh * LSEQ + j) * EDIM);
        float acc = 0.f;
        #pragma unroll
        for (int e4 = 0; e4 < 16; ++e4) {
            float4 kv = kr[e4];
            acc += q[e4 * 4 + 0] * kv.x + q[e4 * 4 + 1] * kv.y +
                   q[e4 * 4 + 2] * kv.z + q[e4 * 4 + 3] * kv.w;
        }
        s = acc * 0.125f;   // 1/sqrt(64)
    }
    // chunk max
    red[tid] = s; __syncthreads();
    for (int t = 128; t >= 1; t >>= 1) { if (tid < t) red[tid] = fmaxf(red[tid], red[tid + t]); __syncthreads(); }
    const float mc = red[0];
    __syncthreads();
    // exp + chunk sum
    float p = valid ? __expf(s - mc) : 0.f;
    ps[tid] = p;
    red[tid] = p; __syncthreads();
    for (int t = 128; t >= 1; t >>= 1) { if (tid < t) red[tid] += red[tid + t]; __syncthreads(); }
    const float lc = red[0];
    __syncthreads();

    // PV over this chunk: 4 j-partitions x 64 e
    const int e = tid & 63, part = tid >> 6;
    float a = 0.f;
    for (int jj = part; jj < JC; jj += 4)
        a += ps[jj] * Vp[((size_t)bh * LSEQ + c0 + jj) * EDIM + e];
    pacc[part][e] = a;
    __syncthreads();
    if (tid < EDIM) {
        float o = pacc[0][tid] + pacc[1][tid] + pacc[2][tid] + pacc[3][tid];
        Pacc[((size_t)gl * NCHMAX + blockIdx.x) * EDIM + tid] = o;
        if (tid == 0) {
            Pm[gl * NCHMAX + blockIdx.x] = mc;
            Pl[gl * NCHMAX + blockIdx.x] = lc;
        }
    }
}

// ---------------------------------------------------------------------------
// Combine chunk partials -> final attention row, overwrite out.
// One block (64 threads) per (bh, n).
// ---------------------------------------------------------------------------
__global__ __launch_bounds__(64) void attn_reduce(const float* __restrict__ Pm,
                                                  const float* __restrict__ Pl,
                                                  const float* __restrict__ Pacc,
                                                  const int* __restrict__ topk,
                                                  float* __restrict__ out) {
    const int gl = blockIdx.x;
    const int bh = gl / NTOP;
    const int idx = topk[gl];
    const int nch = (idx / JC) + 1;
    const int e = threadIdx.x;

    float M = -INFINITY;
    for (int c = 0; c < nch; ++c) M = fmaxf(M, Pm[gl * NCHMAX + c]);
    float L = 0.f, o = 0.f;
    for (int c = 0; c < nch; ++c) {
        float w = __expf(Pm[gl * NCHMAX + c] - M);
        L += Pl[gl * NCHMAX + c] * w;
        o += Pacc[((size_t)gl * NCHMAX + c) * EDIM + e] * w;
    }
    out[((size_t)bh * LSEQ + idx) * EDIM + e] = o / L;
}

// ---------------------------------------------------------------------------
extern "C" void kernel_launch(void* const* d_in, const int* in_sizes, int n_in,
                              void* d_out, int out_size, void* d_ws, size_t ws_size,
                              hipStream_t stream) {
    const float* q  = (const float*)d_in[0];
    const float* k  = (const float*)d_in[1];
    const float* v  = (const float*)d_in[2];
    const float* Wq = (const float*)d_in[4];
    const float* bq = (const float*)d_in[5];
    const float* Wk = (const float*)d_in[6];
    const float* bk = (const float*)d_in[7];
    const float* Wv = (const float*)d_in[8];
    const float* bv = (const float*)d_in[9];
    const int* samp = (const int*)d_in[10];
    float* out = (float*)d_out;

    float* ws = (float*)d_ws;
    const size_t NPROJ = (size_t)MROWS * DMODEL;    // 4194304
    float* Qp   = ws;
    float* Kp   = Qp + NPROJ;
    float* Vp   = Kp + NPROJ;
    float* Mbuf = Vp + NPROJ;                        // 65536
    float* part = Mbuf + (size_t)BHTOT * LSEQ;       // 65536
    int*  topk  = (int*)(part + (size_t)BHTOT * NCHUNK * EDIM);   // 1280 ints
    float* Pm   = (float*)(topk + BHTOT * NTOP);
    float* Pl   = Pm + (size_t)BHTOT * NTOP * NCHMAX;              // 10240
    float* Pacc = Pl + (size_t)BHTOT * NTOP * NCHMAX;              // 10240
    // Pacc: 1280*8*64 = 655360 floats

    dim3 ggrid(MROWS / 128, DMODEL / 128);
    gemm_bias<<<ggrid, 256, 0, stream>>>(q, Wq, bq, Qp);
    gemm_bias<<<ggrid, 256, 0, stream>>>(k, Wk, bk, Kp);
    gemm_bias<<<ggrid, 256, 0, stream>>>(v, Wv, bv, Vp);

    m_kernel<<<MROWS * NHEADS / 4, 256, 0, stream>>>(Qp, Kp, samp, Mbuf);
    topk_kernel<<<BHTOT, 256, 0, stream>>>(Mbuf, topk);

    cs1<<<BHTOT * NCHUNK, 64, 0, stream>>>(Vp, part);
    cs2<<<8, 256, 0, stream>>>(part);
    cs3<<<BHTOT * NCHUNK, 64, 0, stream>>>(Vp, part, out);

    attn_part<<<dim3(NCHMAX, BHTOT * NTOP), 256, 0, stream>>>(Qp, Kp, Vp, topk, Pm, Pl, Pacc);
    attn_reduce<<<BHTOT * NTOP, 64, 0, stream>>>(Pm, Pl, Pacc, topk, out);
}

// Round 16
// 489.048 us; speedup vs baseline: 1.5764x; 1.1994x over previous
//
#include <hip/hip_runtime.h>
#include <hip/hip_bf16.h>
#include <math.h>

// Problem constants
#define BATCH 4
#define LSEQ 2048
#define DMODEL 512
#define NHEADS 8
#define EDIM 64
#define SAMPK 40
#define NTOP 40
#define BHTOT (BATCH * NHEADS)
#define MROWS (BATCH * LSEQ)   // 8192
#define JC 256                  // attn split-K chunk
#define NCHMAX 8                // LSEQ / JC

// ---------------------------------------------------------------------------
// GEMM: P = X @ W + bias.  X: (8192, 512) f32, W: (512,512) f32 row-major.
// R13: 64x128 tile (was 128x128). 128x128 gave only 256 blocks = 1 block/CU
// = 1 wave/SIMD -> no TLP to hide barriers/loads. 64x128 -> 512 blocks =
// 2 blocks/CU = 2 waves/SIMD. 256 thr, 4x(4+4) micro-tile, K-tile 16.
// NOTE: stays f32 — plain bf16 projections flip top-40 selection (order-stat
// gap ~0.01-0.05 < bf16 dot err ~0.03; flipped index -> absmax ~45 >> 3.38).
// ---------------------------------------------------------------------------
__global__ __launch_bounds__(256) void gemm_bias(const float* __restrict__ X,
                                                 const float* __restrict__ W,
                                                 const float* __restrict__ bias,
                                                 float* __restrict__ P) {
    __shared__ float Xs[16][64 + 4];
    __shared__ float Ws[16][128 + 4];
    const int tid = threadIdx.x;
    const int tx = tid & 15;          // n group: cols tx*4..+3 and 64+tx*4..+3
    const int ty = tid >> 4;          // m group: rows ty*4..+3
    const int m0 = blockIdx.x * 64;
    const int n0 = blockIdx.y * 128;

    float acc0[4][4] = {};
    float acc1[4][4] = {};

    for (int kt = 0; kt < DMODEL; kt += 16) {
        // stage X tile (64 rows x 16 k): thread -> row tid>>2, k-quarter (tid&3)*4
        {
            int r  = tid >> 2;
            int kk = (tid & 3) * 4;
            float4 xv = *reinterpret_cast<const float4*>(&X[(size_t)(m0 + r) * DMODEL + kt + kk]);
            Xs[kk + 0][r] = xv.x; Xs[kk + 1][r] = xv.y;
            Xs[kk + 2][r] = xv.z; Xs[kk + 3][r] = xv.w;
        }
        // stage W tile (16 k x 128 n): thread -> k row tid>>4, n chunk (tid&15)*8
        {
            int kk = tid >> 4;
            int nn = (tid & 15) * 8;
            const float* src = &W[(size_t)(kt + kk) * DMODEL + n0 + nn];
            float4 w0 = *reinterpret_cast<const float4*>(src);
            float4 w1 = *reinterpret_cast<const float4*>(src + 4);
            *reinterpret_cast<float4*>(&Ws[kk][nn]) = w0;
            *reinterpret_cast<float4*>(&Ws[kk][nn + 4]) = w1;
        }
        __syncthreads();
        #pragma unroll
        for (int kk = 0; kk < 16; ++kk) {
            float a[4], b0[4], b1[4];
            #pragma unroll
            for (int i = 0; i < 4; ++i) a[i] = Xs[kk][ty * 4 + i];
            #pragma unroll
            for (int j = 0; j < 4; ++j) b0[j] = Ws[kk][tx * 4 + j];
            #pragma unroll
            for (int j = 0; j < 4; ++j) b1[j] = Ws[kk][64 + tx * 4 + j];
            #pragma unroll
            for (int i = 0; i < 4; ++i) {
                #pragma unroll
                for (int j = 0; j < 4; ++j) {
                    acc0[i][j] = fmaf(a[i], b0[j], acc0[i][j]);
                    acc1[i][j] = fmaf(a[i], b1[j], acc1[i][j]);
                }
            }
        }
        __syncthreads();
    }
    #pragma unroll
    for (int i = 0; i < 4; ++i) {
        int m = m0 + ty * 4 + i;
        float4 o0, o1;
        o0.x = acc0[i][0] + bias[n0 + tx * 4 + 0];
        o0.y = acc0[i][1] + bias[n0 + tx * 4 + 1];
        o0.z = acc0[i][2] + bias[n0 + tx * 4 + 2];
        o0.w = acc0[i][3] + bias[n0 + tx * 4 + 3];
        o1.x = acc1[i][0] + bias[n0 + 64 + tx * 4 + 0];
        o1.y = acc1[i][1] + bias[n0 + 64 + tx * 4 + 1];
        o1.z = acc1[i][2] + bias[n0 + 64 + tx * 4 + 2];
        o1.w = acc1[i][3] + bias[n0 + 64 + tx * 4 + 3];
        *reinterpret_cast<float4*>(&P[(size_t)m * DMODEL + n0 + tx * 4]) = o0;
        *reinterpret_cast<float4*>(&P[(size_t)m * DMODEL + n0 + 64 + tx * 4]) = o1;
    }
}

// ---------------------------------------------------------------------------
// M[b,h,l] = max_s dot(q_l, k_samp) - sum_s dot(q_l, k_samp) / L
// One wave per (bh,l). Lane = s4*16 + eg: 4 samples/iter, 16 lanes each
// handling float4 of e. 10 iters. 44 cross-lane ops/wave (was 246).
// Measured: fell out of top-5 (179 us -> <50 us) in R10 profile.
// ---------------------------------------------------------------------------
__global__ __launch_bounds__(256) void m_kernel(const float* __restrict__ Qp,
                                                const float* __restrict__ Kp,
                                                const int* __restrict__ samp,
                                                float* __restrict__ M) {
    const int wid = threadIdx.x >> 6;
    const int lane = threadIdx.x & 63;
    const int gl = blockIdx.x * 4 + wid;           // (bh, l) flat
    const int bh = gl >> 11;
    const int l  = gl & (LSEQ - 1);
    const int s4 = lane >> 4;                      // sample sub-slot 0..3
    const int eg = lane & 15;                      // e-group 0..15

    const float4 qv = *reinterpret_cast<const float4*>(&Qp[(size_t)gl * EDIM + eg * 4]);
    const float* Kb = Kp + (size_t)bh * LSEQ * EDIM;
    const int* srow = samp + l * SAMPK;

    float mx = -INFINITY, sm = 0.f;
    #pragma unroll
    for (int t = 0; t < SAMPK / 4; ++t) {
        const int idx = srow[t * 4 + s4];
        const float4 kv = *reinterpret_cast<const float4*>(&Kb[(size_t)idx * EDIM + eg * 4]);
        float p = qv.x * kv.x + qv.y * kv.y + qv.z * kv.z + qv.w * kv.w;
        // reduce over the 16 lanes of this sample group
        p += __shfl_xor(p, 1);
        p += __shfl_xor(p, 2);
        p += __shfl_xor(p, 4);
        p += __shfl_xor(p, 8);
        mx = fmaxf(mx, p);
        sm += p;
    }
    // combine the 4 sample groups (each lane now has its group's max/sum)
    mx = fmaxf(mx, __shfl_xor(mx, 16));
    sm += __shfl_xor(sm, 16);
    mx = fmaxf(mx, __shfl_xor(mx, 32));
    sm += __shfl_xor(sm, 32);

    if (lane == 0) M[gl] = mx - sm * (1.0f / (float)LSEQ);
}

// ---------------------------------------------------------------------------
// Top-40 indices of M[bh, 0..2047]  (iterative argmax, ties -> lower index)
// ---------------------------------------------------------------------------
__global__ __launch_bounds__(256) void topk_kernel(const float* __restrict__ M,
                                                   int* __restrict__ topk) {
    __shared__ float vals[LSEQ];
    __shared__ float rv[256];
    __shared__ int   ri[256];
    const int bh = blockIdx.x, tid = threadIdx.x;
    for (int i = tid; i < LSEQ; i += 256) vals[i] = M[bh * LSEQ + i];
    __syncthreads();
    for (int t = 0; t < NTOP; ++t) {
        float best = -INFINITY; int bi = LSEQ;
        for (int i = tid; i < LSEQ; i += 256) {
            float v = vals[i];
            if (v > best || (v == best && i < bi)) { best = v; bi = i; }
        }
        rv[tid] = best; ri[tid] = bi;
        __syncthreads();
        for (int s = 128; s >= 1; s >>= 1) {
            if (tid < s) {
                float v2 = rv[tid + s]; int i2 = ri[tid + s];
                if (v2 > rv[tid] || (v2 == rv[tid] && i2 < ri[tid])) { rv[tid] = v2; ri[tid] = i2; }
            }
            __syncthreads();
        }
        if (tid == 0) { topk[bh * NTOP + t] = ri[0]; vals[ri[0]] = -INFINITY; }
        __syncthreads();
    }
}

// ---------------------------------------------------------------------------
// Cumsum of V over l, 3-phase. NCHUNK=32 chunks of 64 rows.
// ---------------------------------------------------------------------------
#define NCHUNK 32
#define CHLEN  64
__global__ __launch_bounds__(64) void cs1(const float* __restrict__ Vp, float* __restrict__ part) {
    const int bh = blockIdx.x >> 5, c = blockIdx.x & 31, e = threadIdx.x;
    const float* vb = Vp + ((size_t)bh * LSEQ + (size_t)c * CHLEN) * EDIM;
    float s = 0.f;
    for (int l = 0; l < CHLEN; ++l) s += vb[(size_t)l * EDIM + e];
    part[((size_t)bh * NCHUNK + c) * EDIM + e] = s;
}
__global__ __launch_bounds__(256) void cs2(float* __restrict__ part) {
    const int t = blockIdx.x * 256 + threadIdx.x;   // 0..2047 = (bh,e)
    const int bh = t >> 6, e = t & 63;
    float run = 0.f;
    for (int c = 0; c < NCHUNK; ++c) {
        float* p = &part[((size_t)bh * NCHUNK + c) * EDIM + e];
        float v = *p; *p = run; run += v;
    }
}
__global__ __launch_bounds__(64) void cs3(const float* __restrict__ Vp,
                                          const float* __restrict__ part,
                                          float* __restrict__ out) {
    const int bh = blockIdx.x >> 5, c = blockIdx.x & 31, e = threadIdx.x;
    const float* vb = Vp + ((size_t)bh * LSEQ + (size_t)c * CHLEN) * EDIM;
    float* ob = out + ((size_t)bh * LSEQ + (size_t)c * CHLEN) * EDIM;
    float run = part[((size_t)bh * NCHUNK + c) * EDIM + e];
    for (int l = 0; l < CHLEN; ++l) {
        run += vb[(size_t)l * EDIM + e];
        ob[(size_t)l * EDIM + e] = run;
    }
}

// ---------------------------------------------------------------------------
// Split-K attention partials: one block per (bh*NTOP+n, chunk).
// R10 rework: was 154 us, latency-bound (VALUBusy 11%, ~20 barriers/block,
// 64 serial scalar V loads/thread). Now: wave-shfl reductions (4 barriers),
// PV as 16 float4 coalesced loads/thread (thread = j-part x e4).
// ---------------------------------------------------------------------------
__global__ __launch_bounds__(256) void attn_part(const float* __restrict__ Qp,
                                                 const float* __restrict__ Kp,
                                                 const float* __restrict__ Vp,
                                                 const int* __restrict__ topk,
                                                 float* __restrict__ Pm,
                                                 float* __restrict__ Pl,
                                                 float* __restrict__ Pacc) {
    __shared__ float q[EDIM];
    __shared__ float ps[JC];
    __shared__ float wred[8];            // [0..3] wave max, [4..7] wave sum
    __shared__ float pacc[16][EDIM];     // 16 j-parts x 64 e
    const int gl = blockIdx.y;           // bh*NTOP + n
    const int bh = gl / NTOP;
    const int idx = topk[gl];
    const int c0 = blockIdx.x * JC;
    if (c0 > idx) return;
    const int tid = threadIdx.x;
    const int lane = tid & 63, wv = tid >> 6;

    if (tid < EDIM) q[tid] = Qp[((size_t)bh * LSEQ + idx) * EDIM + tid];
    __syncthreads();

    const int j = c0 + tid;
    const bool valid = (j <= idx);
    float s = -INFINITY;
    if (valid) {
        const float4* kr = reinterpret_cast<const float4*>(Kp + ((size_t)bh * LSEQ + j) * EDIM);
        float acc = 0.f;
        #pragma unroll
        for (int e4 = 0; e4 < 16; ++e4) {
            float4 kv = kr[e4];
            acc += q[e4 * 4 + 0] * kv.x + q[e4 * 4 + 1] * kv.y +
                   q[e4 * 4 + 2] * kv.z + q[e4 * 4 + 3] * kv.w;
        }
        s = acc * 0.125f;   // 1/sqrt(64)
    }

    // chunk max: wave shfl reduce, then 4-way LDS combine
    float wm = s;
    #pragma unroll
    for (int off = 32; off >= 1; off >>= 1) wm = fmaxf(wm, __shfl_xor(wm, off));
    if (lane == 0) wred[wv] = wm;
    __syncthreads();
    const float mc = fmaxf(fmaxf(wred[0], wred[1]), fmaxf(wred[2], wred[3]));

    // exp + chunk sum (ps[] write covered by the same barrier as wred[4..7])
    float p = valid ? __expf(s - mc) : 0.f;
    ps[tid] = p;
    float wsum = p;
    #pragma unroll
    for (int off = 32; off >= 1; off >>= 1) wsum += __shfl_xor(wsum, off);
    if (lane == 0) wred[4 + wv] = wsum;
    __syncthreads();
    const float lc = wred[4] + wred[5] + wred[6] + wred[7];

    // PV: thread = (part = tid>>4 in 0..15, e4 = tid&15). 16 float4 loads,
    // each wave instruction covers 4 contiguous 256B rows (coalesced).
    const int part = tid >> 4, e4 = tid & 15;
    float4 a = {0.f, 0.f, 0.f, 0.f};
    for (int jj = part; jj < JC; jj += 16) {
        const float4 v4 = *reinterpret_cast<const float4*>(
            Vp + ((size_t)bh * LSEQ + c0 + jj) * EDIM + e4 * 4);
        const float pw = ps[jj];
        a.x += pw * v4.x; a.y += pw * v4.y; a.z += pw * v4.z; a.w += pw * v4.w;
    }
    *reinterpret_cast<float4*>(&pacc[part][e4 * 4]) = a;
    __syncthreads();
    if (tid < EDIM) {
        float o = 0.f;
        #pragma unroll
        for (int pp = 0; pp < 16; ++pp) o += pacc[pp][tid];
        Pacc[((size_t)gl * NCHMAX + blockIdx.x) * EDIM + tid] = o;
        if (tid == 0) {
            Pm[gl * NCHMAX + blockIdx.x] = mc;
            Pl[gl * NCHMAX + blockIdx.x] = lc;
        }
    }
}

// ---------------------------------------------------------------------------
// Combine chunk partials -> final attention row, overwrite out.
// One block (64 threads) per (bh, n).
// ---------------------------------------------------------------------------
__global__ __launch_bounds__(64) void attn_reduce(const float* __restrict__ Pm,
                                                  const float* __restrict__ Pl,
                                                  const float* __restrict__ Pacc,
                                                  const int* __restrict__ topk,
                                                  float* __restrict__ out) {
    const int gl = blockIdx.x;
    const int bh = gl / NTOP;
    const int idx = topk[gl];
    const int nch = (idx / JC) + 1;
    const int e = threadIdx.x;

    float M = -INFINITY;
    for (int c = 0; c < nch; ++c) M = fmaxf(M, Pm[gl * NCHMAX + c]);
    float L = 0.f, o = 0.f;
    for (int c = 0; c < nch; ++c) {
        float w = __expf(Pm[gl * NCHMAX + c] - M);
        L += Pl[gl * NCHMAX + c] * w;
        o += Pacc[((size_t)gl * NCHMAX + c) * EDIM + e] * w;
    }
    out[((size_t)bh * LSEQ + idx) * EDIM + e] = o / L;
}

// ---------------------------------------------------------------------------
extern "C" void kernel_launch(void* const* d_in, const int* in_sizes, int n_in,
                              void* d_out, int out_size, void* d_ws, size_t ws_size,
                              hipStream_t stream) {
    const float* q  = (const float*)d_in[0];
    const float* k  = (const float*)d_in[1];
    const float* v  = (const float*)d_in[2];
    const float* Wq = (const float*)d_in[4];
    const float* bq = (const float*)d_in[5];
    const float* Wk = (const float*)d_in[6];
    const float* bk = (const float*)d_in[7];
    const float* Wv = (const float*)d_in[8];
    const float* bv = (const float*)d_in[9];
    const int* samp = (const int*)d_in[10];
    float* out = (float*)d_out;

    float* ws = (float*)d_ws;
    const size_t NPROJ = (size_t)MROWS * DMODEL;    // 4194304
    float* Qp   = ws;
    float* Kp   = Qp + NPROJ;
    float* Vp   = Kp + NPROJ;
    float* Mbuf = Vp + NPROJ;                        // 65536
    float* part = Mbuf + (size_t)BHTOT * LSEQ;       // 65536
    int*  topk  = (int*)(part + (size_t)BHTOT * NCHUNK * EDIM);   // 1280 ints
    float* Pm   = (float*)(topk + BHTOT * NTOP);
    float* Pl   = Pm + (size_t)BHTOT * NTOP * NCHMAX;              // 10240
    float* Pacc = Pl + (size_t)BHTOT * NTOP * NCHMAX;              // 10240
    // Pacc: 1280*8*64 = 655360 floats

    dim3 ggrid(MROWS / 64, DMODEL / 128);
    gemm_bias<<<ggrid, 256, 0, stream>>>(q, Wq, bq, Qp);
    gemm_bias<<<ggrid, 256, 0, stream>>>(k, Wk, bk, Kp);
    gemm_bias<<<ggrid, 256, 0, stream>>>(v, Wv, bv, Vp);

    m_kernel<<<MROWS * NHEADS / 4, 256, 0, stream>>>(Qp, Kp, samp, Mbuf);
    topk_kernel<<<BHTOT, 256, 0, stream>>>(Mbuf, topk);

    cs1<<<BHTOT * NCHUNK, 64, 0, stream>>>(Vp, part);
    cs2<<<8, 256, 0, stream>>>(part);
    cs3<<<BHTOT * NCHUNK, 64, 0, stream>>>(Vp, part, out);

    attn_part<<<dim3(NCHMAX, BHTOT * NTOP), 256, 0, stream>>>(Qp, Kp, Vp, topk, Pm, Pl, Pacc);
    attn_reduce<<<BHTOT * NTOP, 64, 0, stream>>>(Pm, Pl, Pacc, topk, out);
}